// Round 1
// baseline (234.703 us; speedup 1.0000x reference)
//
#include <hip/hip_runtime.h>

#define NC 256
#define FH 36
#define FW 36
#define SCALE (1.0f/16.0f)

__device__ __forceinline__ float g_fn(float u) {
    // antiderivative of triangular kernel, clipped to [-1, 1]
    u = fminf(1.0f, fmaxf(-1.0f, u));
    if (u < 0.0f) { float t = u + 1.0f; return 0.5f * t * t; }
    else          { float t = 1.0f - u; return 1.0f - 0.5f * t * t; }
}

__global__ __launch_bounds__(256) void filterpool_kernel(
    const float* __restrict__ feat,
    const float* __restrict__ bb,
    float* __restrict__ out)
{
    const int n    = blockIdx.x;    // roi index 0..127
    const int cg   = blockIdx.y;    // channel group 0..63
    const int t    = threadIdx.x;
    const int lane = t & 63;
    const int wave = t >> 6;        // 0..3
    const int c    = cg * 4 + wave;

    __shared__ float wx[FW];
    __shared__ float wy[FH];

    const float bx = bb[n*4+0], by = bb[n*4+1];
    const float bw = bb[n*4+2], bh = bb[n*4+3];
    const float x0 = bx * SCALE,        y0 = by * SCALE;
    const float x1 = (bx + bw) * SCALE, y1 = (by + bh) * SCALE;

    if (t < FW) {
        float fw = (float)t;
        wx[t] = g_fn(x1 - fw) - g_fn(x0 - fw);
    } else if (t < FW + FH) {
        int h = t - FW;
        float fh = (float)h;
        wy[h] = g_fn(y1 - fh) - g_fn(y0 - fh);
    }
    __syncthreads();

    // Each wave reduces one contiguous 36x36 channel tile. 36/4 = 9 float4
    // per row, so every float4 sits inside a single row: h = q/9, w0 = (q%9)*4.
    const float4* fptr = (const float4*)(feat + ((size_t)n * NC + c) * (FH * FW));
    float acc = 0.0f;
    #pragma unroll 2
    for (int q = lane; q < (FH * FW) / 4; q += 64) {
        float4 v = fptr[q];
        int h  = q / 9;
        int w0 = (q - h * 9) * 4;
        float wyh = wy[h];
        acc += wyh * (v.x * wx[w0]     + v.y * wx[w0 + 1]
                    + v.z * wx[w0 + 2] + v.w * wx[w0 + 3]);
    }

    // 64-lane wave reduction
    #pragma unroll
    for (int off = 32; off > 0; off >>= 1)
        acc += __shfl_down(acc, off, 64);

    if (lane == 0) {
        float bin_w = x1 - x0, bin_h = y1 - y0;
        float area = fmaxf(bin_w, 0.0f) * fmaxf(bin_h, 0.0f);
        float res  = (area > 0.0f) ? (acc / fmaxf(area, 1e-30f)) : 0.0f;
        out[(size_t)n * NC + c] = res;
    }
}

extern "C" void kernel_launch(void* const* d_in, const int* in_sizes, int n_in,
                              void* d_out, int out_size, void* d_ws, size_t ws_size,
                              hipStream_t stream) {
    const float* feat = (const float*)d_in[0];
    const float* bb   = (const float*)d_in[1];
    float* out        = (float*)d_out;
    dim3 grid(128, 64);   // (roi, channel-group-of-4)
    filterpool_kernel<<<grid, 256, 0, stream>>>(feat, bb, out);
}